// Round 11
// baseline (894.798 us; speedup 1.0000x reference)
//
#include <hip/hip_runtime.h>
#include <math.h>

// ---------------- problem constants ----------------
#define NN   50000      // nodes
#define NR   500        // relations
#define E1N  200000     // direct edges
#define E2N  50000      // 2-hop edges
#define EN   250000     // total edges
#define ALPHAC 0.2f

// ---------------- workspace layout (bytes) — R10-identical ----------------
#define OFF_OUT1  ((size_t)0)           // 50000*256*4 = 51,200,000
#define OFF_EE1   ((size_t)51200000)    // 2*250000*4
#define OFF_EE2   ((size_t)53200000)    // 250000*4
#define OFF_W1    ((size_t)54200000)    // 768*4
#define OFF_W2    ((size_t)54203072)    // 768*4
#define OFF_DEG   ((size_t)54206144)
#define OFF_OFFS  ((size_t)54406144)
#define OFF_CUR   ((size_t)54606208)
#define OFF_BSUM  ((size_t)54806208)
#define OFF_CARRY ((size_t)54807232)
#define OFF_CSR   ((size_t)54808256)    // 250000*4
#define OFF_AHH   ((size_t)55808256)    // 256*384*2 (aH bf16 hi)
#define OFF_AHL   ((size_t)56004864)
#define OFF_AOH   ((size_t)56201472)    // 256*768*2 (aO bf16 hi)
#define OFF_AOL   ((size_t)56594688)
// total ~57.0 MB

typedef __attribute__((ext_vector_type(8))) short bf16x8;
typedef __attribute__((ext_vector_type(4))) short short4v;
typedef __attribute__((ext_vector_type(2))) short short2v;
typedef __attribute__((ext_vector_type(4))) float f4;
typedef __attribute__((ext_vector_type(2))) float f2;
typedef __attribute__((ext_vector_type(4))) float f32x4;

__device__ __forceinline__ float lrelu(float x) { return x > 0.f ? x : ALPHAC * x; }
__device__ __forceinline__ float eluf(float x)  { return x > 0.f ? x : expm1f(x); }

__device__ __forceinline__ short bfh(float x) {
    union { float f; unsigned u; } c; c.f = x;
    unsigned r = (c.u + 0x7FFFu + ((c.u >> 16) & 1u)) >> 16;
    return (short)r;
}
__device__ __forceinline__ float bf2f(short h) {
    union { unsigned u; float f; } c; c.u = ((unsigned)(unsigned short)h) << 16;
    return c.f;
}

__device__ __forceinline__ void decode_edge(int e, const int* el1, const int* rt1,
                                            const int* el2, const int* rtn,
                                            int& src, int& dst, int& ra, int& rb) {
    if (e < E1N) {
        src = el1[e]; dst = el1[E1N + e]; ra = rt1[e]; rb = -1;
    } else {
        int j = e - E1N;
        src = el2[j]; dst = el2[E2N + j]; ra = rtn[2 * j]; rb = rtn[2 * j + 1];
    }
}

// ---------------- w = a2 @ a precompute (R3-verbatim) ----------------
__global__ void k_w(const float* aH, const float* a2H, const float* aO, const float* a2O,
                    float* w1, float* w2) {
    int t = blockIdx.x * blockDim.x + threadIdx.x;
    if (t < 768) {
        int h = t / 384; int r = t - h * 384; int seg = r >> 7; int j = r & 127;
        const float* A  = aH + (size_t)h * 128 * 384;
        const float* a2 = a2H + h * 128;
        float s = 0.f;
        for (int d = 0; d < 128; ++d) {
            const float* row = A + d * 384;
            float c;
            if (seg == 0)      c = row[j]       + row[256 + j];
            else if (seg == 1) c = row[128 + j] + row[256 + j];
            else               c = row[256 + j];
            s += a2[d] * c;
        }
        w1[t] = s;
    } else if (t < 1536) {
        int r = t - 768; int seg = r >> 8; int j = r & 255;
        float s = 0.f;
        for (int d = 0; d < 256; ++d) s += a2O[d] * aO[d * 768 + seg * 256 + j];
        w2[r] = s;
    }
}

// ---------------- split-bf16 conversion (R3-verbatim) ----------------
__global__ void k_conv(const float* aH, const float* aO,
                       short* ahh, short* ahl, short* aoh, short* aol) {
    int t = blockIdx.x * 256 + threadIdx.x;
    if (t < 98304) {
        float x = aH[t];
        short hi = bfh(x);
        ahh[t] = hi; ahl[t] = bfh(x - bf2f(hi));
    } else if (t < 294912) {
        int i = t - 98304;
        float x = aO[i];
        short hi = bfh(x);
        aoh[i] = hi; aol[i] = bfh(x - bf2f(hi));
    }
}

// ---------------- out_rel = rel @ W (R3-verbatim) ----------------
__global__ void k_outrel(const float* rel, const float* W, float* outrel) {
    int r = blockIdx.x; int c = threadIdx.x;
    const float* rr = rel + r * 128;
    float s = 0.f;
    for (int k = 0; k < 128; ++k) s += rr[k] * W[k * 256 + c];
    outrel[r * 256 + c] = s;
}

// ---------------- CSR build (R3-verbatim) ----------------
__global__ void k_deg(const int* el1, const int* el2, int* deg) {
    int e = blockIdx.x * 256 + threadIdx.x;
    if (e >= EN) return;
    int src = (e < E1N) ? el1[e] : el2[e - E1N];
    atomicAdd(&deg[src], 1);
}

__global__ void k_scan1(const int* deg, int* offs, int* bsum) {
    __shared__ int s[256];
    int t = threadIdx.x; int i = blockIdx.x * 256 + t;
    int v = (i < NN) ? deg[i] : 0;
    s[t] = v; __syncthreads();
    for (int off = 1; off < 256; off <<= 1) {
        int x = (t >= off) ? s[t - off] : 0;
        __syncthreads(); s[t] += x; __syncthreads();
    }
    if (i < NN) offs[i] = s[t] - v;
    if (t == 255) bsum[blockIdx.x] = s[255];
}

__global__ void k_scan2(int* bsum, int* carry) {
    __shared__ int s[256];
    int t = threadIdx.x;
    int v = (t < 196) ? bsum[t] : 0;
    s[t] = v; __syncthreads();
    for (int off = 1; off < 256; off <<= 1) {
        int x = (t >= off) ? s[t - off] : 0;
        __syncthreads(); s[t] += x; __syncthreads();
    }
    if (t < 196) carry[t] = s[t] - v;
}

__global__ void k_scan3(int* offs, const int* carry) {
    int i = blockIdx.x * 256 + threadIdx.x;
    if (i < NN) offs[i] += carry[blockIdx.x];
}

__global__ void k_scatter(const int* el1, const int* el2, const int* offs,
                          int* cursor, int* csr) {
    int e = blockIdx.x * 256 + threadIdx.x;
    if (e >= EN) return;
    int src = (e < E1N) ? el1[e] : el2[e - E1N];
    int pos = offs[src] + atomicAdd(&cursor[src], 1);
    csr[pos] = e;
}

// ---------------- deterministic CSR sort (R10-verbatim) ----------------
__global__ void k_sortcsr(const int* offs, int* csr) {
    int nid = blockIdx.x * 4 + (threadIdx.x >> 6);
    int lane = threadIdx.x & 63;
    if (nid >= NN) return;
    int start = offs[nid];
    int end = (nid == NN - 1) ? EN : offs[nid + 1];
    int len = end - start;
    if (len <= 1) return;
    if (len <= 64) {
        int key = (lane < len) ? csr[start + lane] : 0x7FFFFFFF;
        int rank = 0;
        #pragma unroll
        for (int j = 0; j < 64; ++j) {
            int kj = __shfl(key, j, 64);
            rank += (kj < key) ? 1 : 0;
        }
        if (lane < len) csr[start + rank] = key;
    } else if (lane == 0) {
        for (int i = start + 1; i < end; ++i) {
            int k = csr[i]; int j = i - 1;
            while (j >= start && csr[j] > k) { csr[j + 1] = csr[j]; --j; }
            csr[j + 1] = k;
        }
    }
}

// ---------------- layer-1 edge_e (R3-verbatim) ----------------
__global__ void k_ee1(const float* ent, const float* rel,
                      const int* el1, const int* rt1, const int* el2, const int* rtn,
                      const float* w1, float* ee) {
    int wid  = (blockIdx.x * blockDim.x + threadIdx.x) >> 6;
    int lane = threadIdx.x & 63;
    int e0 = wid * 8;
    if (e0 >= EN) return;
    int d0 = lane, d1 = lane + 64;
    float wA00 = w1[d0],       wA01 = w1[d1];
    float wB00 = w1[128 + d0], wB01 = w1[128 + d1];
    float wC00 = w1[256 + d0], wC01 = w1[256 + d1];
    float wA10 = w1[384 + d0], wA11 = w1[384 + d1];
    float wB10 = w1[512 + d0], wB11 = w1[512 + d1];
    float wC10 = w1[640 + d0], wC11 = w1[640 + d1];
    int eend = min(e0 + 8, EN);
    for (int e = e0; e < eend; ++e) {
        int src, dst, ra, rb;
        decode_edge(e, el1, rt1, el2, rtn, src, dst, ra, rb);
        float es0 = ent[src * 128 + d0], es1 = ent[src * 128 + d1];
        float ed0 = ent[dst * 128 + d0], ed1 = ent[dst * 128 + d1];
        float rp0 = rel[ra * 128 + d0],  rp1 = rel[ra * 128 + d1];
        if (rb >= 0) { rp0 += rel[rb * 128 + d0]; rp1 += rel[rb * 128 + d1]; }
        float t0 = es0 * wA00 + es1 * wA01 + ed0 * wB00 + ed1 * wB01 + rp0 * wC00 + rp1 * wC01;
        float t1 = es0 * wA10 + es1 * wA11 + ed0 * wB10 + ed1 * wB11 + rp0 * wC10 + rp1 * wC11;
        #pragma unroll
        for (int off = 32; off; off >>= 1) {
            t0 += __shfl_xor(t0, off, 64);
            t1 += __shfl_xor(t1, off, 64);
        }
        if (lane == 0) {
            ee[e]      = expf(-lrelu(t0));
            ee[EN + e] = expf(-lrelu(t1));
        }
    }
}

// ---------------- layer-1 aggregate + MFMA GEMM + elu ----------------
// R10 shell (1024 threads, wave-per-node). ONLY change vs R10: gather loop
// 4-chunked — loads for 4 edges issued before any accumulation (MLP), then
// accumulated in identical order. Value-identical to R10's rolled loop.
#define PK1 392   // 384 + 8 pad (shorts)
__global__ __launch_bounds__(1024) void k_agg1(
        const float* ent, const float* rel,
        const int* el1, const int* rt1, const int* el2, const int* rtn,
        const int* offs, const int* csr, const float* ee,
        const short* ahh, const short* ahl, float* out1) {
    __shared__ __align__(16) short Yh[16 * 2 * PK1];
    __shared__ __align__(16) short Yl[16 * 2 * PK1];
    __shared__ float RS[16][2];
    int w = threadIdx.x >> 6;          // 0..15 == node slot m
    int lane = threadIdx.x & 63;
    {
        int m = w;
        int n = blockIdx.x * 16 + m;
        int start = offs[n];
        int end = (n == NN - 1) ? EN : offs[n + 1];
        f2 en = *(const f2*)&ent[n * 128 + 2 * lane];
        f2 s2a = {0, 0}, sea = {0, 0}, s2b = {0, 0}, seb = {0, 0};
        float rs0 = 0.f, rs1 = 0.f;
        for (int idx = start; idx < end; idx += 4) {
            int cnt = end - idx;
            float e0v[4], e1v[4];
            f2 gg[4], rp[4];
            #pragma unroll
            for (int u = 0; u < 4; ++u) {
                if (u < cnt) {
                    int e = csr[idx + u];
                    int src, dst, ra, rb;
                    decode_edge(e, el1, rt1, el2, rtn, src, dst, ra, rb);
                    e0v[u] = ee[e]; e1v[u] = ee[EN + e];
                    gg[u] = *(const f2*)&ent[dst * 128 + 2 * lane];
                    f2 r = *(const f2*)&rel[ra * 128 + 2 * lane];
                    if (rb >= 0) r += *(const f2*)&rel[rb * 128 + 2 * lane];
                    rp[u] = r;
                }
            }
            #pragma unroll
            for (int u = 0; u < 4; ++u) {
                if (u < cnt) {
                    f2 em = rp[u] + en + gg[u];
                    s2a += e0v[u] * gg[u]; sea += e0v[u] * em;
                    s2b += e1v[u] * gg[u]; seb += e1v[u] * em;
                    rs0 += e0v[u]; rs1 += e1v[u];
                }
            }
        }
        f2 regs[2][3] = {{rs0 * en, s2a, sea}, {rs1 * en, s2b, seb}};
        #pragma unroll
        for (int hh = 0; hh < 2; ++hh) {
            #pragma unroll
            for (int rg = 0; rg < 3; ++rg) {
                int base = m * 2 * PK1 + hh * PK1 + rg * 128 + 2 * lane;
                short2v vh, vl;
                #pragma unroll
                for (int j = 0; j < 2; ++j) {
                    float v = regs[hh][rg][j];
                    vh[j] = bfh(v);
                    vl[j] = bfh(v - bf2f(vh[j]));
                }
                *(short2v*)&Yh[base] = vh;
                *(short2v*)&Yl[base] = vl;
            }
        }
        if (lane == 0) { RS[m][0] = rs0; RS[m][1] = rs1; }
    }
    __syncthreads();

    int r = lane & 15, g = lane >> 4;
    int ct = w;
    int h = w >> 3;
    const short* YhB = &Yh[r * 2 * PK1 + h * PK1];
    const short* YlB = &Yl[r * 2 * PK1 + h * PK1];
    const short* B0h = ahh + (size_t)(ct * 16 + r) * 384;
    const short* B0l = ahl + (size_t)(ct * 16 + r) * 384;
    f32x4 z = {0.f, 0.f, 0.f, 0.f};
    f32x4 hh0 = z, hl0 = z, lh0 = z;
    for (int kt = 0; kt < 12; ++kt) {
        int ko = kt * 32 + g * 8;
        bf16x8 yh = *(const bf16x8*)(YhB + ko);
        bf16x8 yl = *(const bf16x8*)(YlB + ko);
        bf16x8 b0h = *(const bf16x8*)(B0h + ko);
        bf16x8 b0l = *(const bf16x8*)(B0l + ko);
        hh0 = __builtin_amdgcn_mfma_f32_16x16x32_bf16(yh, b0h, hh0, 0, 0, 0);
        hl0 = __builtin_amdgcn_mfma_f32_16x16x32_bf16(yl, b0h, hl0, 0, 0, 0);
        lh0 = __builtin_amdgcn_mfma_f32_16x16x32_bf16(yh, b0l, lh0, 0, 0, 0);
    }
    f32x4 acc0 = hh0 + hl0 + lh0;
    #pragma unroll
    for (int q = 0; q < 4; ++q) {
        int m = g * 4 + q;
        float rs = RS[m][h];
        float denom = (rs == 0.f) ? 1e-12f : rs;
        size_t row = (size_t)(blockIdx.x * 16 + m) * 256;
        out1[row + ct * 16 + r] = eluf(acc0[q] / denom);
    }
}

// ---------------- layer-2 edge_e (R3-verbatim) ----------------
__global__ void k_ee2(const float* out1, const float* orel,
                      const int* el1, const int* rt1, const int* el2, const int* rtn,
                      const float* w2, float* ee2) {
    int wid  = (blockIdx.x * blockDim.x + threadIdx.x) >> 6;
    int lane = threadIdx.x & 63;
    int e0 = wid * 8;
    if (e0 >= EN) return;
    f4 wS = *(const f4*)&w2[4 * lane];
    f4 wD = *(const f4*)&w2[256 + 4 * lane];
    f4 wE = *(const f4*)&w2[512 + 4 * lane];
    int eend = min(e0 + 8, EN);
    for (int e = e0; e < eend; ++e) {
        int src, dst, ra, rb;
        decode_edge(e, el1, rt1, el2, rtn, src, dst, ra, rb);
        f4 xs = *(const f4*)&out1[(size_t)src * 256 + 4 * lane];
        f4 xd = *(const f4*)&out1[(size_t)dst * 256 + 4 * lane];
        f4 em = *(const f4*)&orel[ra * 256 + 4 * lane];
        if (rb >= 0) em += *(const f4*)&orel[rb * 256 + 4 * lane] + xs + xd;
        f4 tv = xs * wS + xd * wD + em * wE;
        float t = tv[0] + tv[1] + tv[2] + tv[3];
        #pragma unroll
        for (int off = 32; off; off >>= 1) t += __shfl_xor(t, off, 64);
        if (lane == 0) ee2[e] = expf(-lrelu(t));
    }
}

// ---------------- layer-2 aggregate + MFMA GEMM + elu ----------------
// R10 shell; gather loop 4-chunked (value-identical accumulation order).
#define PK2 776   // 768 + 8 pad (shorts)
__global__ __launch_bounds__(1024) void k_agg2(
        const float* out1, const float* orel,
        const int* el1, const int* rt1, const int* el2, const int* rtn,
        const int* offs, const int* csr, const float* ee2,
        const short* aoh, const short* aol, float* out_ent) {
    __shared__ __align__(16) short Yh[16 * PK2];
    __shared__ __align__(16) short Yl[16 * PK2];
    __shared__ float RS[16];
    int w = threadIdx.x >> 6;
    int lane = threadIdx.x & 63;
    {
        int m = w;
        int n = blockIdx.x * 16 + m;
        int start = offs[n];
        int end = (n == NN - 1) ? EN : offs[n + 1];
        f4 on = *(const f4*)&out1[(size_t)n * 256 + 4 * lane];
        f4 s2 = {0, 0, 0, 0}, se = {0, 0, 0, 0};
        float rs = 0.f;
        for (int idx = start; idx < end; idx += 4) {
            int cnt = end - idx;
            float ev[4];
            f4 xx[4], em[4];
            #pragma unroll
            for (int u = 0; u < 4; ++u) {
                if (u < cnt) {
                    int e = csr[idx + u];
                    int src, dst, ra, rb;
                    decode_edge(e, el1, rt1, el2, rtn, src, dst, ra, rb);
                    ev[u] = ee2[e];
                    xx[u] = *(const f4*)&out1[(size_t)dst * 256 + 4 * lane];
                    f4 m_ = *(const f4*)&orel[ra * 256 + 4 * lane];
                    if (rb >= 0) m_ += *(const f4*)&orel[rb * 256 + 4 * lane] + on + xx[u];
                    em[u] = m_;
                }
            }
            #pragma unroll
            for (int u = 0; u < 4; ++u) {
                if (u < cnt) {
                    s2 += ev[u] * xx[u];
                    se += ev[u] * em[u];
                    rs += ev[u];
                }
            }
        }
        f4 regs[3] = {rs * on, s2, se};
        #pragma unroll
        for (int rg = 0; rg < 3; ++rg) {
            int base = m * PK2 + rg * 256 + 4 * lane;
            short4v vh, vl;
            #pragma unroll
            for (int j = 0; j < 4; ++j) {
                float v = regs[rg][j];
                vh[j] = bfh(v);
                vl[j] = bfh(v - bf2f(vh[j]));
            }
            *(short4v*)&Yh[base] = vh;
            *(short4v*)&Yl[base] = vl;
        }
        if (lane == 0) RS[m] = rs;
    }
    __syncthreads();

    int r = lane & 15, g = lane >> 4;
    int ct = w;
    const short* YhB = &Yh[r * PK2];
    const short* YlB = &Yl[r * PK2];
    const short* B0h = aoh + (size_t)(ct * 16 + r) * 768;
    const short* B0l = aol + (size_t)(ct * 16 + r) * 768;
    f32x4 z = {0.f, 0.f, 0.f, 0.f};
    f32x4 hh0 = z, hl0 = z, lh0 = z;
    for (int kt = 0; kt < 24; ++kt) {
        int ko = kt * 32 + g * 8;
        bf16x8 yh = *(const bf16x8*)(YhB + ko);
        bf16x8 yl = *(const bf16x8*)(YlB + ko);
        bf16x8 b0h = *(const bf16x8*)(B0h + ko);
        bf16x8 b0l = *(const bf16x8*)(B0l + ko);
        hh0 = __builtin_amdgcn_mfma_f32_16x16x32_bf16(yh, b0h, hh0, 0, 0, 0);
        hl0 = __builtin_amdgcn_mfma_f32_16x16x32_bf16(yl, b0h, hl0, 0, 0, 0);
        lh0 = __builtin_amdgcn_mfma_f32_16x16x32_bf16(yh, b0l, lh0, 0, 0, 0);
    }
    f32x4 acc0 = hh0 + hl0 + lh0;
    #pragma unroll
    for (int q = 0; q < 4; ++q) {
        int m = g * 4 + q;
        float rs = RS[m];
        float denom = (rs == 0.f) ? 1e-12f : rs;
        size_t row = (size_t)(blockIdx.x * 16 + m) * 256;
        out_ent[row + ct * 16 + r] = eluf(acc0[q] / denom);
    }
}

extern "C" void kernel_launch(void* const* d_in, const int* in_sizes, int n_in,
                              void* d_out, int out_size, void* d_ws, size_t ws_size,
                              hipStream_t stream) {
    const float* ent = (const float*)d_in[0];
    const float* rel = (const float*)d_in[1];
    const int*   el1 = (const int*)d_in[2];
    const int*   rt1 = (const int*)d_in[3];
    const int*   el2 = (const int*)d_in[4];
    const int*   rtn = (const int*)d_in[5];
    const float* aH  = (const float*)d_in[6];
    const float* a2H = (const float*)d_in[7];
    const float* W   = (const float*)d_in[8];
    const float* aO  = (const float*)d_in[9];
    const float* a2O = (const float*)d_in[10];

    float* out_ent = (float*)d_out;                       // [50000,256]
    float* out_rel = (float*)d_out + (size_t)NN * 256;    // [500,256]

    char* ws = (char*)d_ws;
    float* out1   = (float*)(ws + OFF_OUT1);
    float* ee1b   = (float*)(ws + OFF_EE1);
    float* ee2b   = (float*)(ws + OFF_EE2);
    float* w1     = (float*)(ws + OFF_W1);
    float* w2     = (float*)(ws + OFF_W2);
    int*   deg    = (int*)(ws + OFF_DEG);
    int*   offs   = (int*)(ws + OFF_OFFS);
    int*   cur    = (int*)(ws + OFF_CUR);
    int*   bsum   = (int*)(ws + OFF_BSUM);
    int*   carry  = (int*)(ws + OFF_CARRY);
    int*   csr    = (int*)(ws + OFF_CSR);
    short* ahh    = (short*)(ws + OFF_AHH);
    short* ahl    = (short*)(ws + OFF_AHL);
    short* aoh    = (short*)(ws + OFF_AOH);
    short* aol    = (short*)(ws + OFF_AOL);

    hipMemsetAsync(deg, 0, (size_t)NN * 4, stream);
    hipMemsetAsync(cur, 0, (size_t)NN * 4, stream);

    k_w<<<6, 256, 0, stream>>>(aH, a2H, aO, a2O, w1, w2);
    k_conv<<<1152, 256, 0, stream>>>(aH, aO, ahh, ahl, aoh, aol);
    k_outrel<<<NR, 256, 0, stream>>>(rel, W, out_rel);

    k_deg<<<(EN + 255) / 256, 256, 0, stream>>>(el1, el2, deg);
    k_scan1<<<(NN + 255) / 256, 256, 0, stream>>>(deg, offs, bsum);
    k_scan2<<<1, 256, 0, stream>>>(bsum, carry);
    k_scan3<<<(NN + 255) / 256, 256, 0, stream>>>(offs, carry);
    k_scatter<<<(EN + 255) / 256, 256, 0, stream>>>(el1, el2, offs, cur, csr);
    k_sortcsr<<<(NN + 3) / 4, 256, 0, stream>>>(offs, csr);

    int ee_blocks = (EN / 8 + 3) / 4 + 1;
    k_ee1<<<ee_blocks, 256, 0, stream>>>(ent, rel, el1, rt1, el2, rtn, w1, ee1b);
    k_agg1<<<NN / 16, 1024, 0, stream>>>(ent, rel, el1, rt1, el2, rtn,
                                         offs, csr, ee1b, ahh, ahl, out1);
    k_ee2<<<ee_blocks, 256, 0, stream>>>(out1, out_rel, el1, rt1, el2, rtn, w2, ee2b);
    k_agg2<<<NN / 16, 1024, 0, stream>>>(out1, out_rel, el1, rt1, el2, rtn,
                                         offs, csr, ee2b, aoh, aol, out_ent);
}

// Round 12
// 733.188 us; speedup vs baseline: 1.2204x; 1.2204x over previous
//
#include <hip/hip_runtime.h>
#include <math.h>

// ---------------- problem constants ----------------
#define NN   50000      // nodes
#define NR   500        // relations
#define E1N  200000     // direct edges
#define E2N  50000      // 2-hop edges
#define EN   250000     // total edges
#define ALPHAC 0.2f

// ---------------- workspace layout (bytes) ----------------
#define OFF_OUT1  ((size_t)0)           // 50000*256*4 = 51,200,000
#define OFF_EE1   ((size_t)51200000)    // 2*250000*4  (CSR-ordered, layer1 both heads)
#define OFF_EE2   ((size_t)53200000)    // 250000*4    (CSR-ordered)
#define OFF_W1    ((size_t)54200000)    // 768*4
#define OFF_W2    ((size_t)54203072)    // 768*4
#define OFF_DEG   ((size_t)54206144)
#define OFF_OFFS  ((size_t)54406144)
#define OFF_CUR   ((size_t)54606208)
#define OFF_BSUM  ((size_t)54806208)
#define OFF_CARRY ((size_t)54807232)
#define OFF_CSR   ((size_t)54808256)    // 250000*4
#define OFF_AHH   ((size_t)55808256)    // 256*384*2 (aH bf16 hi)
#define OFF_AHL   ((size_t)56004864)
#define OFF_AOH   ((size_t)56201472)    // 256*768*2 (aO bf16 hi)
#define OFF_AOL   ((size_t)56594688)
#define OFF_DESC  ((size_t)56987904)    // 250000*16 = 4,000,000 (int4 per CSR slot)
// total ~61.0 MB

typedef __attribute__((ext_vector_type(8))) short bf16x8;
typedef __attribute__((ext_vector_type(4))) short short4v;
typedef __attribute__((ext_vector_type(2))) short short2v;
typedef __attribute__((ext_vector_type(4))) float f4;
typedef __attribute__((ext_vector_type(2))) float f2;
typedef __attribute__((ext_vector_type(4))) float f32x4;

__device__ __forceinline__ float lrelu(float x) { return x > 0.f ? x : ALPHAC * x; }
__device__ __forceinline__ float eluf(float x)  { return x > 0.f ? x : expm1f(x); }

__device__ __forceinline__ short bfh(float x) {
    union { float f; unsigned u; } c; c.f = x;
    unsigned r = (c.u + 0x7FFFu + ((c.u >> 16) & 1u)) >> 16;
    return (short)r;
}
__device__ __forceinline__ float bf2f(short h) {
    union { unsigned u; float f; } c; c.u = ((unsigned)(unsigned short)h) << 16;
    return c.f;
}

__device__ __forceinline__ void decode_edge(int e, const int* el1, const int* rt1,
                                            const int* el2, const int* rtn,
                                            int& src, int& dst, int& ra, int& rb) {
    if (e < E1N) {
        src = el1[e]; dst = el1[E1N + e]; ra = rt1[e]; rb = -1;
    } else {
        int j = e - E1N;
        src = el2[j]; dst = el2[E2N + j]; ra = rtn[2 * j]; rb = rtn[2 * j + 1];
    }
}

// ---------------- w = a2 @ a precompute (R3-verbatim) ----------------
__global__ void k_w(const float* aH, const float* a2H, const float* aO, const float* a2O,
                    float* w1, float* w2) {
    int t = blockIdx.x * blockDim.x + threadIdx.x;
    if (t < 768) {
        int h = t / 384; int r = t - h * 384; int seg = r >> 7; int j = r & 127;
        const float* A  = aH + (size_t)h * 128 * 384;
        const float* a2 = a2H + h * 128;
        float s = 0.f;
        for (int d = 0; d < 128; ++d) {
            const float* row = A + d * 384;
            float c;
            if (seg == 0)      c = row[j]       + row[256 + j];
            else if (seg == 1) c = row[128 + j] + row[256 + j];
            else               c = row[256 + j];
            s += a2[d] * c;
        }
        w1[t] = s;
    } else if (t < 1536) {
        int r = t - 768; int seg = r >> 8; int j = r & 255;
        float s = 0.f;
        for (int d = 0; d < 256; ++d) s += a2O[d] * aO[d * 768 + seg * 256 + j];
        w2[r] = s;
    }
}

// ---------------- split-bf16 conversion (R3-verbatim) ----------------
__global__ void k_conv(const float* aH, const float* aO,
                       short* ahh, short* ahl, short* aoh, short* aol) {
    int t = blockIdx.x * 256 + threadIdx.x;
    if (t < 98304) {
        float x = aH[t];
        short hi = bfh(x);
        ahh[t] = hi; ahl[t] = bfh(x - bf2f(hi));
    } else if (t < 294912) {
        int i = t - 98304;
        float x = aO[i];
        short hi = bfh(x);
        aoh[i] = hi; aol[i] = bfh(x - bf2f(hi));
    }
}

// ---------------- out_rel = rel @ W (R3-verbatim) ----------------
__global__ void k_outrel(const float* rel, const float* W, float* outrel) {
    int r = blockIdx.x; int c = threadIdx.x;
    const float* rr = rel + r * 128;
    float s = 0.f;
    for (int k = 0; k < 128; ++k) s += rr[k] * W[k * 256 + c];
    outrel[r * 256 + c] = s;
}

// ---------------- CSR build (R3-verbatim) ----------------
__global__ void k_deg(const int* el1, const int* el2, int* deg) {
    int e = blockIdx.x * 256 + threadIdx.x;
    if (e >= EN) return;
    int src = (e < E1N) ? el1[e] : el2[e - E1N];
    atomicAdd(&deg[src], 1);
}

__global__ void k_scan1(const int* deg, int* offs, int* bsum) {
    __shared__ int s[256];
    int t = threadIdx.x; int i = blockIdx.x * 256 + t;
    int v = (i < NN) ? deg[i] : 0;
    s[t] = v; __syncthreads();
    for (int off = 1; off < 256; off <<= 1) {
        int x = (t >= off) ? s[t - off] : 0;
        __syncthreads(); s[t] += x; __syncthreads();
    }
    if (i < NN) offs[i] = s[t] - v;
    if (t == 255) bsum[blockIdx.x] = s[255];
}

__global__ void k_scan2(int* bsum, int* carry) {
    __shared__ int s[256];
    int t = threadIdx.x;
    int v = (t < 196) ? bsum[t] : 0;
    s[t] = v; __syncthreads();
    for (int off = 1; off < 256; off <<= 1) {
        int x = (t >= off) ? s[t - off] : 0;
        __syncthreads(); s[t] += x; __syncthreads();
    }
    if (t < 196) carry[t] = s[t] - v;
}

__global__ void k_scan3(int* offs, const int* carry) {
    int i = blockIdx.x * 256 + threadIdx.x;
    if (i < NN) offs[i] += carry[blockIdx.x];
}

__global__ void k_scatter(const int* el1, const int* el2, const int* offs,
                          int* cursor, int* csr) {
    int e = blockIdx.x * 256 + threadIdx.x;
    if (e >= EN) return;
    int src = (e < E1N) ? el1[e] : el2[e - E1N];
    int pos = offs[src] + atomicAdd(&cursor[src], 1);
    csr[pos] = e;
}

// ---------------- deterministic CSR sort (R10-verbatim) ----------------
__global__ void k_sortcsr(const int* offs, int* csr) {
    int nid = blockIdx.x * 4 + (threadIdx.x >> 6);
    int lane = threadIdx.x & 63;
    if (nid >= NN) return;
    int start = offs[nid];
    int end = (nid == NN - 1) ? EN : offs[nid + 1];
    int len = end - start;
    if (len <= 1) return;
    if (len <= 64) {
        int key = (lane < len) ? csr[start + lane] : 0x7FFFFFFF;
        int rank = 0;
        #pragma unroll
        for (int j = 0; j < 64; ++j) {
            int kj = __shfl(key, j, 64);
            rank += (kj < key) ? 1 : 0;
        }
        if (lane < len) csr[start + rank] = key;
    } else if (lane == 0) {
        for (int i = start + 1; i < end; ++i) {
            int k = csr[i]; int j = i - 1;
            while (j >= start && csr[j] > k) { csr[j + 1] = csr[j]; --j; }
            csr[j + 1] = k;
        }
    }
}

// ---------------- NEW: packed edge descriptors in CSR order ----------------
// desc[idx] = (dst, ra, rb, src) for edge csr[idx]. One-time coalesced pass;
// removes the decode round-trip from every downstream per-edge chain.
__global__ void k_desc(const int* csr, const int* el1, const int* rt1,
                       const int* el2, const int* rtn, int4* desc) {
    int idx = blockIdx.x * 256 + threadIdx.x;
    if (idx >= EN) return;
    int e = csr[idx];
    int src, dst, ra, rb;
    decode_edge(e, el1, rt1, el2, rtn, src, dst, ra, rb);
    desc[idx] = make_int4(dst, ra, rb, src);
}

// ---------------- layer-1 edge_e (R3 math, CSR order via desc) ----------
__global__ void k_ee1(const float* ent, const float* rel, const int4* desc,
                      const float* w1, float* ee) {
    int wid  = (blockIdx.x * blockDim.x + threadIdx.x) >> 6;
    int lane = threadIdx.x & 63;
    int i0 = wid * 8;
    if (i0 >= EN) return;
    int d0 = lane, d1 = lane + 64;
    float wA00 = w1[d0],       wA01 = w1[d1];
    float wB00 = w1[128 + d0], wB01 = w1[128 + d1];
    float wC00 = w1[256 + d0], wC01 = w1[256 + d1];
    float wA10 = w1[384 + d0], wA11 = w1[384 + d1];
    float wB10 = w1[512 + d0], wB11 = w1[512 + d1];
    float wC10 = w1[640 + d0], wC11 = w1[640 + d1];
    int iend = min(i0 + 8, EN);
    for (int idx = i0; idx < iend; ++idx) {
        int4 d = desc[idx];
        int dst = d.x, ra = d.y, rb = d.z, src = d.w;
        float es0 = ent[src * 128 + d0], es1 = ent[src * 128 + d1];
        float ed0 = ent[dst * 128 + d0], ed1 = ent[dst * 128 + d1];
        float rp0 = rel[ra * 128 + d0],  rp1 = rel[ra * 128 + d1];
        if (rb >= 0) { rp0 += rel[rb * 128 + d0]; rp1 += rel[rb * 128 + d1]; }
        float t0 = es0 * wA00 + es1 * wA01 + ed0 * wB00 + ed1 * wB01 + rp0 * wC00 + rp1 * wC01;
        float t1 = es0 * wA10 + es1 * wA11 + ed0 * wB10 + ed1 * wB11 + rp0 * wC10 + rp1 * wC11;
        #pragma unroll
        for (int off = 32; off; off >>= 1) {
            t0 += __shfl_xor(t0, off, 64);
            t1 += __shfl_xor(t1, off, 64);
        }
        if (lane == 0) {
            ee[idx]      = expf(-lrelu(t0));
            ee[EN + idx] = expf(-lrelu(t1));
        }
    }
}

// ---------------- layer-1 aggregate + MFMA GEMM + elu ----------------
// R10 shell (1024 threads, wave-per-node, rolled loop). ONLY change: edge
// decode/ee loads come from desc[idx]/ee[idx] — affine addresses, off the
// dependent chain. Arithmetic and accumulation order identical to R10.
#define PK1 392   // 384 + 8 pad (shorts)
__global__ __launch_bounds__(1024) void k_agg1(
        const float* ent, const float* rel, const int4* desc,
        const int* offs, const float* ee,
        const short* ahh, const short* ahl, float* out1) {
    __shared__ __align__(16) short Yh[16 * 2 * PK1];
    __shared__ __align__(16) short Yl[16 * 2 * PK1];
    __shared__ float RS[16][2];
    int w = threadIdx.x >> 6;          // 0..15 == node slot m
    int lane = threadIdx.x & 63;
    {
        int m = w;
        int n = blockIdx.x * 16 + m;
        int start = offs[n];
        int end = (n == NN - 1) ? EN : offs[n + 1];
        f2 en = *(const f2*)&ent[n * 128 + 2 * lane];
        f2 s2a = {0, 0}, sea = {0, 0}, s2b = {0, 0}, seb = {0, 0};
        float rs0 = 0.f, rs1 = 0.f;
        for (int idx = start; idx < end; ++idx) {
            int4 d = desc[idx];
            float e0v = ee[idx], e1v = ee[EN + idx];
            f2 gg = *(const f2*)&ent[d.x * 128 + 2 * lane];
            f2 rp = *(const f2*)&rel[d.y * 128 + 2 * lane];
            if (d.z >= 0) rp += *(const f2*)&rel[d.z * 128 + 2 * lane];
            f2 em = rp + en + gg;
            s2a += e0v * gg; sea += e0v * em;
            s2b += e1v * gg; seb += e1v * em;
            rs0 += e0v; rs1 += e1v;
        }
        f2 regs[2][3] = {{rs0 * en, s2a, sea}, {rs1 * en, s2b, seb}};
        #pragma unroll
        for (int hh = 0; hh < 2; ++hh) {
            #pragma unroll
            for (int rg = 0; rg < 3; ++rg) {
                int base = m * 2 * PK1 + hh * PK1 + rg * 128 + 2 * lane;
                short2v vh, vl;
                #pragma unroll
                for (int j = 0; j < 2; ++j) {
                    float v = regs[hh][rg][j];
                    vh[j] = bfh(v);
                    vl[j] = bfh(v - bf2f(vh[j]));
                }
                *(short2v*)&Yh[base] = vh;
                *(short2v*)&Yl[base] = vl;
            }
        }
        if (lane == 0) { RS[m][0] = rs0; RS[m][1] = rs1; }
    }
    __syncthreads();

    int r = lane & 15, g = lane >> 4;
    int ct = w;
    int h = w >> 3;
    const short* YhB = &Yh[r * 2 * PK1 + h * PK1];
    const short* YlB = &Yl[r * 2 * PK1 + h * PK1];
    const short* B0h = ahh + (size_t)(ct * 16 + r) * 384;
    const short* B0l = ahl + (size_t)(ct * 16 + r) * 384;
    f32x4 z = {0.f, 0.f, 0.f, 0.f};
    f32x4 hh0 = z, hl0 = z, lh0 = z;
    for (int kt = 0; kt < 12; ++kt) {
        int ko = kt * 32 + g * 8;
        bf16x8 yh = *(const bf16x8*)(YhB + ko);
        bf16x8 yl = *(const bf16x8*)(YlB + ko);
        bf16x8 b0h = *(const bf16x8*)(B0h + ko);
        bf16x8 b0l = *(const bf16x8*)(B0l + ko);
        hh0 = __builtin_amdgcn_mfma_f32_16x16x32_bf16(yh, b0h, hh0, 0, 0, 0);
        hl0 = __builtin_amdgcn_mfma_f32_16x16x32_bf16(yl, b0h, hl0, 0, 0, 0);
        lh0 = __builtin_amdgcn_mfma_f32_16x16x32_bf16(yh, b0l, lh0, 0, 0, 0);
    }
    f32x4 acc0 = hh0 + hl0 + lh0;
    #pragma unroll
    for (int q = 0; q < 4; ++q) {
        int m = g * 4 + q;
        float rs = RS[m][h];
        float denom = (rs == 0.f) ? 1e-12f : rs;
        size_t row = (size_t)(blockIdx.x * 16 + m) * 256;
        out1[row + ct * 16 + r] = eluf(acc0[q] / denom);
    }
}

// ---------------- layer-2 edge_e (R3 math, CSR order via desc) ----------
__global__ void k_ee2(const float* out1, const float* orel, const int4* desc,
                      const float* w2, float* ee2) {
    int wid  = (blockIdx.x * blockDim.x + threadIdx.x) >> 6;
    int lane = threadIdx.x & 63;
    int i0 = wid * 8;
    if (i0 >= EN) return;
    f4 wS = *(const f4*)&w2[4 * lane];
    f4 wD = *(const f4*)&w2[256 + 4 * lane];
    f4 wE = *(const f4*)&w2[512 + 4 * lane];
    int iend = min(i0 + 8, EN);
    for (int idx = i0; idx < iend; ++idx) {
        int4 d = desc[idx];
        f4 xs = *(const f4*)&out1[(size_t)d.w * 256 + 4 * lane];
        f4 xd = *(const f4*)&out1[(size_t)d.x * 256 + 4 * lane];
        f4 em = *(const f4*)&orel[d.y * 256 + 4 * lane];
        if (d.z >= 0) em += *(const f4*)&orel[d.z * 256 + 4 * lane] + xs + xd;
        f4 tv = xs * wS + xd * wD + em * wE;
        float t = tv[0] + tv[1] + tv[2] + tv[3];
        #pragma unroll
        for (int off = 32; off; off >>= 1) t += __shfl_xor(t, off, 64);
        if (lane == 0) ee2[idx] = expf(-lrelu(t));
    }
}

// ---------------- layer-2 aggregate + MFMA GEMM + elu ----------------
// R10 shell; desc/ee-indexed loads (affine), rolled loop.
#define PK2 776   // 768 + 8 pad (shorts)
__global__ __launch_bounds__(1024) void k_agg2(
        const float* out1, const float* orel, const int4* desc,
        const int* offs, const float* ee2,
        const short* aoh, const short* aol, float* out_ent) {
    __shared__ __align__(16) short Yh[16 * PK2];
    __shared__ __align__(16) short Yl[16 * PK2];
    __shared__ float RS[16];
    int w = threadIdx.x >> 6;
    int lane = threadIdx.x & 63;
    {
        int m = w;
        int n = blockIdx.x * 16 + m;
        int start = offs[n];
        int end = (n == NN - 1) ? EN : offs[n + 1];
        f4 on = *(const f4*)&out1[(size_t)n * 256 + 4 * lane];
        f4 s2 = {0, 0, 0, 0}, se = {0, 0, 0, 0};
        float rs = 0.f;
        for (int idx = start; idx < end; ++idx) {
            int4 d = desc[idx];
            float ev = ee2[idx];
            f4 gg = *(const f4*)&out1[(size_t)d.x * 256 + 4 * lane];
            f4 em = *(const f4*)&orel[d.y * 256 + 4 * lane];
            if (d.z >= 0) em += *(const f4*)&orel[d.z * 256 + 4 * lane] + on + gg;
            s2 += ev * gg;
            se += ev * em;
            rs += ev;
        }
        f4 regs[3] = {rs * on, s2, se};
        #pragma unroll
        for (int rg = 0; rg < 3; ++rg) {
            int base = m * PK2 + rg * 256 + 4 * lane;
            short4v vh, vl;
            #pragma unroll
            for (int j = 0; j < 4; ++j) {
                float v = regs[rg][j];
                vh[j] = bfh(v);
                vl[j] = bfh(v - bf2f(vh[j]));
            }
            *(short4v*)&Yh[base] = vh;
            *(short4v*)&Yl[base] = vl;
        }
        if (lane == 0) RS[m] = rs;
    }
    __syncthreads();

    int r = lane & 15, g = lane >> 4;
    int ct = w;
    const short* YhB = &Yh[r * PK2];
    const short* YlB = &Yl[r * PK2];
    const short* B0h = aoh + (size_t)(ct * 16 + r) * 768;
    const short* B0l = aol + (size_t)(ct * 16 + r) * 768;
    f32x4 z = {0.f, 0.f, 0.f, 0.f};
    f32x4 hh0 = z, hl0 = z, lh0 = z;
    for (int kt = 0; kt < 24; ++kt) {
        int ko = kt * 32 + g * 8;
        bf16x8 yh = *(const bf16x8*)(YhB + ko);
        bf16x8 yl = *(const bf16x8*)(YlB + ko);
        bf16x8 b0h = *(const bf16x8*)(B0h + ko);
        bf16x8 b0l = *(const bf16x8*)(B0l + ko);
        hh0 = __builtin_amdgcn_mfma_f32_16x16x32_bf16(yh, b0h, hh0, 0, 0, 0);
        hl0 = __builtin_amdgcn_mfma_f32_16x16x32_bf16(yl, b0h, hl0, 0, 0, 0);
        lh0 = __builtin_amdgcn_mfma_f32_16x16x32_bf16(yh, b0l, lh0, 0, 0, 0);
    }
    f32x4 acc0 = hh0 + hl0 + lh0;
    #pragma unroll
    for (int q = 0; q < 4; ++q) {
        int m = g * 4 + q;
        float rs = RS[m];
        float denom = (rs == 0.f) ? 1e-12f : rs;
        size_t row = (size_t)(blockIdx.x * 16 + m) * 256;
        out_ent[row + ct * 16 + r] = eluf(acc0[q] / denom);
    }
}

extern "C" void kernel_launch(void* const* d_in, const int* in_sizes, int n_in,
                              void* d_out, int out_size, void* d_ws, size_t ws_size,
                              hipStream_t stream) {
    const float* ent = (const float*)d_in[0];
    const float* rel = (const float*)d_in[1];
    const int*   el1 = (const int*)d_in[2];
    const int*   rt1 = (const int*)d_in[3];
    const int*   el2 = (const int*)d_in[4];
    const int*   rtn = (const int*)d_in[5];
    const float* aH  = (const float*)d_in[6];
    const float* a2H = (const float*)d_in[7];
    const float* W   = (const float*)d_in[8];
    const float* aO  = (const float*)d_in[9];
    const float* a2O = (const float*)d_in[10];

    float* out_ent = (float*)d_out;                       // [50000,256]
    float* out_rel = (float*)d_out + (size_t)NN * 256;    // [500,256]

    char* ws = (char*)d_ws;
    float* out1   = (float*)(ws + OFF_OUT1);
    float* ee1b   = (float*)(ws + OFF_EE1);
    float* ee2b   = (float*)(ws + OFF_EE2);
    float* w1     = (float*)(ws + OFF_W1);
    float* w2     = (float*)(ws + OFF_W2);
    int*   deg    = (int*)(ws + OFF_DEG);
    int*   offs   = (int*)(ws + OFF_OFFS);
    int*   cur    = (int*)(ws + OFF_CUR);
    int*   bsum   = (int*)(ws + OFF_BSUM);
    int*   carry  = (int*)(ws + OFF_CARRY);
    int*   csr    = (int*)(ws + OFF_CSR);
    short* ahh    = (short*)(ws + OFF_AHH);
    short* ahl    = (short*)(ws + OFF_AHL);
    short* aoh    = (short*)(ws + OFF_AOH);
    short* aol    = (short*)(ws + OFF_AOL);
    int4*  desc   = (int4*)(ws + OFF_DESC);

    hipMemsetAsync(deg, 0, (size_t)NN * 4, stream);
    hipMemsetAsync(cur, 0, (size_t)NN * 4, stream);

    k_w<<<6, 256, 0, stream>>>(aH, a2H, aO, a2O, w1, w2);
    k_conv<<<1152, 256, 0, stream>>>(aH, aO, ahh, ahl, aoh, aol);
    k_outrel<<<NR, 256, 0, stream>>>(rel, W, out_rel);

    k_deg<<<(EN + 255) / 256, 256, 0, stream>>>(el1, el2, deg);
    k_scan1<<<(NN + 255) / 256, 256, 0, stream>>>(deg, offs, bsum);
    k_scan2<<<1, 256, 0, stream>>>(bsum, carry);
    k_scan3<<<(NN + 255) / 256, 256, 0, stream>>>(offs, carry);
    k_scatter<<<(EN + 255) / 256, 256, 0, stream>>>(el1, el2, offs, cur, csr);
    k_sortcsr<<<(NN + 3) / 4, 256, 0, stream>>>(offs, csr);
    k_desc<<<(EN + 255) / 256, 256, 0, stream>>>(csr, el1, rt1, el2, rtn, desc);

    int ee_blocks = (EN / 8 + 3) / 4 + 1;
    k_ee1<<<ee_blocks, 256, 0, stream>>>(ent, rel, desc, w1, ee1b);
    k_agg1<<<NN / 16, 1024, 0, stream>>>(ent, rel, desc, offs, ee1b,
                                         ahh, ahl, out1);
    k_ee2<<<ee_blocks, 256, 0, stream>>>(out1, out_rel, desc, w2, ee2b);
    k_agg2<<<NN / 16, 1024, 0, stream>>>(out1, out_rel, desc, offs, ee2b,
                                         aoh, aol, out_ent);
}